// Round 7
// baseline (5246.230 us; speedup 1.0000x reference)
//
#include <hip/hip_runtime.h>
#include <hip/hip_bf16.h>

#define T_SEQ 512
#define BATCH 64
#define IN0   128
#define HID   512
#define OUTF  256
#define G4    (4*HID)     // 2048 gate rows
#define NWG_L 32          // workgroups per layer (each owns 16 hidden units)
#define NTHR  512         // 8 waves per WG

typedef __attribute__((ext_vector_type(8))) short short8;   // 8 bf16 (MFMA A/B frag)
typedef __attribute__((ext_vector_type(4))) float f32x4;    // MFMA C/D frag
typedef unsigned short u16;
typedef unsigned long long u64;

__device__ __forceinline__ float sigmoidf_(float x) { return 1.f / (1.f + __expf(-x)); }
__device__ __forceinline__ float tanhf_(float x)    { return 1.f - 2.f / (1.f + __expf(2.f * x)); }

__device__ __forceinline__ u16 f2bf(float f) {
    union { float f; unsigned u; } a; a.f = f;
    unsigned u = a.u;
    return (u16)((u + 0x7fffu + ((u >> 16) & 1u)) >> 16);   // RNE
}

// Packed-flag poll: the layer's 32 flags live in ONE 128B line. Each lane
// reads one u64 (2 flags, 8-way lane duplication) -> poll iteration touches
// 1 line instead of 64. Relaxed agent loads; rare acquire as progress net.
__device__ __forceinline__ void poll_packed_ge(const unsigned* flags, int lane, unsigned tgt) {
    const u64* p = reinterpret_cast<const u64*>(flags) + (lane & 15);
    unsigned it = 0;
    for (;;) {
        u64 v = __hip_atomic_load(p, __ATOMIC_RELAXED, __HIP_MEMORY_SCOPE_AGENT);
        unsigned lo = (unsigned)v, hi = (unsigned)(v >> 32);
        if (__all((int)(lo >= tgt && hi >= tgt))) return;
        __builtin_amdgcn_s_sleep(1);
        if ((++it & 2047u) == 0u)
            (void)__hip_atomic_load(p, __ATOMIC_ACQUIRE, __HIP_MEMORY_SCOPE_AGENT);
    }
}

// ---------------- f32 -> bf16 conversion ----------------
__global__ void cvt_f32_bf16(const float* __restrict__ in, u16* __restrict__ out, int n4) {
    int i = blockIdx.x * blockDim.x + threadIdx.x;
    if (i < n4) {
        float4 v = reinterpret_cast<const float4*>(in)[i];
        ushort4 o;
        o.x = f2bf(v.x); o.y = f2bf(v.y); o.z = f2bf(v.z); o.w = f2bf(v.w);
        reinterpret_cast<ushort4*>(out)[i] = o;
    }
}

// ---------------- fused pipelined 2-layer LSTM ----------------
// WG g in [0,32): layer 0, owns hidden units [16g,16g+16) -> 64 gate cols as
// 4 MFMA col-tiles (tile nt: units 16g+4nt..+3, cols q = gate*4 + du).
// WG 32+g: layer 1, same ownership. 8 waves: wave w -> batch rows
// 16(w&3)..+15, col-tiles {2(w>>2), 2(w>>2)+1}.
// flags[g] (packed, one line per layer) = #steps completed by WG g.
template<int LAYER>
__device__ __forceinline__ void run_layer(
    const u16* __restrict__ asrc,   // L0: x_bf [T,B,128]; L1: y0 [T,B,512]
    const u16* __restrict__ wih, const u16* __restrict__ whh,
    const float* __restrict__ bias,
    u16* __restrict__ ybuf,         // own-layer h/y storage [T,B,512]
    float* __restrict__ hNout, float* __restrict__ cNout,
    unsigned* flags_own, unsigned* flags_dep, int g,
    u16 (*lds_w)[32][512], float (*lds_g)[65], float (*lds_b)[16],
    unsigned (*lds_h)[8])
{
    constexpr int KIN = (LAYER == 0) ? IN0 : HID;
    constexpr int KS1 = KIN / 32;        // input-part K slices
    constexpr int KS  = KS1 + 16;        // + recurrent K slices

    const int tid  = threadIdx.x;
    const int lane = tid & 63;
    const int w    = tid >> 6;           // wave id 0..7
    const int bq   = w & 3;              // batch quarter -> rows 16bq..16bq+15
    const int cp   = w >> 2;             // col-tile pair -> tiles 2cp, 2cp+1
    const int t0n  = 2 * cp, t1n = 2 * cp + 1;
    const int ubase = 16 * g;

    // ---- pack weights into LDS in MFMA B-frag order (4 col-tiles) ----
    for (int idx = tid; idx < 4 * KS * 64; idx += NTHR) {
        int nt  = idx / (KS * 64);
        int rem = idx - nt * (KS * 64);
        int ks = rem >> 6, s = rem & 63, q = s & 15, kq = s >> 4;
        int r = (q >> 2) * HID + ubase + 4 * nt + (q & 3);   // global gate row
        const u16* src = (ks < KS1)
            ? wih + (size_t)r * KIN + (size_t)ks * 32 + kq * 8
            : whh + (size_t)r * HID + (size_t)(ks - KS1) * 32 + kq * 8;
        *reinterpret_cast<uint4*>(&lds_w[nt][ks][s * 8]) =
            *reinterpret_cast<const uint4*>(src);
    }
    if (tid < 64) {
        int nt = tid >> 4, q = tid & 15;
        lds_b[nt][q] = bias[(q >> 2) * HID + ubase + 4 * nt + (q & 3)];
    }
    __syncthreads();

    const int pb  = tid & 63;   // pointwise: batch index
    const int pu2 = tid >> 6;   // pointwise: unit-pair index (0..7)
    float c0 = 0.f, c1 = 0.f;

    const int arow = 16 * bq + (lane & 15);
    const int koff = (lane >> 4) * 8;

    for (int t = 0; t < T_SEQ; ++t) {
        f32x4 ac0[4] = {{0,0,0,0},{0,0,0,0},{0,0,0,0},{0,0,0,0}};
        f32x4 ac1[4] = {{0,0,0,0},{0,0,0,0},{0,0,0,0},{0,0,0,0}};

        if (LAYER == 0) {
            // x[t] contribution — no dependency, runs before any wait
            const u16* ap = asrc + ((size_t)t * BATCH + arow) * KIN + koff;
            short8 a[KS1];
            #pragma unroll
            for (int j = 0; j < KS1; ++j)
                a[j] = *reinterpret_cast<const short8*>(ap + j * 32);
            #pragma unroll
            for (int j = 0; j < KS1; ++j) {
                ac0[j & 3] = __builtin_amdgcn_mfma_f32_16x16x32_bf16(
                    a[j], *reinterpret_cast<const short8*>(&lds_w[t0n][j][lane * 8]), ac0[j & 3], 0, 0, 0);
                ac1[j & 3] = __builtin_amdgcn_mfma_f32_16x16x32_bf16(
                    a[j], *reinterpret_cast<const short8*>(&lds_w[t1n][j][lane * 8]), ac1[j & 3], 0, 0, 0);
            }
        }

        // ---- waits: parallel polls on separate waves, one barrier join ----
        if (LAYER == 0) {
            if (t > 0) {
                if (w == 0) poll_packed_ge(flags_own, lane, (unsigned)t);
                __syncthreads();
            }
        } else {
            if (w == 0 && t > 0) poll_packed_ge(flags_own, lane, (unsigned)t);   // h1[t-1]
            if (w == 1) poll_packed_ge(flags_dep, lane, (unsigned)(t + 1));      // y0[t]
            __syncthreads();
        }

        // own-layer recurrent h[t-1] contribution
        if (t > 0) {
            const u16* hp = ybuf + ((size_t)(t - 1) * BATCH + arow) * HID + koff;
            short8 a[16];
            #pragma unroll
            for (int j = 0; j < 16; ++j)
                a[j] = *reinterpret_cast<const short8*>(hp + j * 32);
            #pragma unroll
            for (int j = 0; j < 16; ++j) {
                ac0[j & 3] = __builtin_amdgcn_mfma_f32_16x16x32_bf16(
                    a[j], *reinterpret_cast<const short8*>(&lds_w[t0n][KS1 + j][lane * 8]), ac0[j & 3], 0, 0, 0);
                ac1[j & 3] = __builtin_amdgcn_mfma_f32_16x16x32_bf16(
                    a[j], *reinterpret_cast<const short8*>(&lds_w[t1n][KS1 + j][lane * 8]), ac1[j & 3], 0, 0, 0);
            }
        }

        // L1: y0[t] contribution
        if (LAYER == 1) {
            const u16* ap = asrc + ((size_t)t * BATCH + arow) * HID + koff;
            short8 a[16];
            #pragma unroll
            for (int j = 0; j < 16; ++j)
                a[j] = *reinterpret_cast<const short8*>(ap + j * 32);
            #pragma unroll
            for (int j = 0; j < 16; ++j) {
                ac0[j & 3] = __builtin_amdgcn_mfma_f32_16x16x32_bf16(
                    a[j], *reinterpret_cast<const short8*>(&lds_w[t0n][j][lane * 8]), ac0[j & 3], 0, 0, 0);
                ac1[j & 3] = __builtin_amdgcn_mfma_f32_16x16x32_bf16(
                    a[j], *reinterpret_cast<const short8*>(&lds_w[t1n][j][lane * 8]), ac1[j & 3], 0, 0, 0);
            }
        }

        f32x4 s0 = (ac0[0] + ac0[1]) + (ac0[2] + ac0[3]);
        f32x4 s1 = (ac1[0] + ac1[1]) + (ac1[2] + ac1[3]);
        // D frag: row = 16bq + (lane>>4)*4 + j (batch), col = lane&15 (q)
        #pragma unroll
        for (int j = 0; j < 4; ++j) {
            int row = 16 * bq + (lane >> 4) * 4 + j;
            lds_g[row][t0n * 16 + (lane & 15)] = s0[j];
            lds_g[row][t1n * 16 + (lane & 15)] = s1[j];
        }
        __syncthreads();

        // pointwise cell update (f32): thread (pb,pu2) owns units 2pu2, 2pu2+1
        {
            const int nt = pu2 >> 1;            // col-tile of these 2 units
            const int dq = (2 * pu2) & 3;       // 0 or 2
            const float* gr = &lds_g[pb][nt * 16];
            const float* br = lds_b[nt];
            float gi0 = sigmoidf_(gr[dq]      + br[dq]);
            float gf0 = sigmoidf_(gr[4 + dq]  + br[4 + dq]);
            float gg0 = tanhf_(   gr[8 + dq]  + br[8 + dq]);
            float go0 = sigmoidf_(gr[12 + dq] + br[12 + dq]);
            c0 = gf0 * c0 + gi0 * gg0;
            float h0v = go0 * tanhf_(c0);
            float gi1 = sigmoidf_(gr[dq + 1]      + br[dq + 1]);
            float gf1 = sigmoidf_(gr[4 + dq + 1]  + br[4 + dq + 1]);
            float gg1 = tanhf_(   gr[8 + dq + 1]  + br[8 + dq + 1]);
            float go1 = sigmoidf_(gr[12 + dq + 1] + br[12 + dq + 1]);
            c1 = gf1 * c1 + gi1 * gg1;
            float h1v = go1 * tanhf_(c1);

            lds_h[pb][pu2] = (unsigned)f2bf(h0v) | ((unsigned)f2bf(h1v) << 16);

            if (t == T_SEQ - 1) {
                hNout[pb * HID + ubase + 2 * pu2]     = h0v;
                hNout[pb * HID + ubase + 2 * pu2 + 1] = h1v;
                cNout[pb * HID + ubase + 2 * pu2]     = c0;
                cNout[pb * HID + ubase + 2 * pu2 + 1] = c1;
            }
        }
        __syncthreads();

        // slim publish: wave 0 stores the WG's whole 2KB block (32B/lane as
        // 4x u64 agent stores), waits only its own acks, then lane 0 raises
        // the flag (single u32 into the packed line). Waves 1-7 run ahead.
        if (w == 0) {
            const unsigned* hr = lds_h[lane];
            u64 q0 = (u64)hr[0] | ((u64)hr[1] << 32);
            u64 q1 = (u64)hr[2] | ((u64)hr[3] << 32);
            u64 q2 = (u64)hr[4] | ((u64)hr[5] << 32);
            u64 q3 = (u64)hr[6] | ((u64)hr[7] << 32);
            u64* yp = reinterpret_cast<u64*>(
                ybuf + ((size_t)t * BATCH + lane) * HID + ubase);
            __hip_atomic_store(yp + 0, q0, __ATOMIC_RELAXED, __HIP_MEMORY_SCOPE_AGENT);
            __hip_atomic_store(yp + 1, q1, __ATOMIC_RELAXED, __HIP_MEMORY_SCOPE_AGENT);
            __hip_atomic_store(yp + 2, q2, __ATOMIC_RELAXED, __HIP_MEMORY_SCOPE_AGENT);
            __hip_atomic_store(yp + 3, q3, __ATOMIC_RELAXED, __HIP_MEMORY_SCOPE_AGENT);
            asm volatile("s_waitcnt vmcnt(0)" ::: "memory");
            if (lane == 0)
                __hip_atomic_store(flags_own + g, (unsigned)(t + 1),
                                   __ATOMIC_RELAXED, __HIP_MEMORY_SCOPE_AGENT);
        }
    }
}

__global__ __launch_bounds__(NTHR, 1)
void lstm_fused(const u16* __restrict__ x_bf,
                const u16* __restrict__ wih0, const u16* __restrict__ whh0, const float* __restrict__ b0,
                const u16* __restrict__ wih1, const u16* __restrict__ whh1, const float* __restrict__ b1,
                u16* __restrict__ y0, u16* __restrict__ y1,
                float* __restrict__ hN, float* __restrict__ cN,
                unsigned* __restrict__ ctr)
{
    __shared__ __align__(16) u16 lds_w[4][32][512];   // 128 KB (L0 uses KS=20 of 32)
    __shared__ float lds_g[BATCH][65];                // 64 gate cols + pad
    __shared__ float lds_b[4][16];
    __shared__ __align__(16) unsigned lds_h[BATCH][8];

    unsigned* flags0 = ctr;        // 32 u32 = one 128B line
    unsigned* flags1 = ctr + 32;   // next 128B line

    const int wgid = blockIdx.x;
    if (wgid < NWG_L) {
        run_layer<0>(x_bf, wih0, whh0, b0, y0, hN, cN,
                     flags0, flags0, wgid, lds_w, lds_g, lds_b, lds_h);
    } else {
        run_layer<1>(y0, wih1, whh1, b1, y1, hN + BATCH * HID, cN + BATCH * HID,
                     flags1, flags0, wgid - NWG_L, lds_w, lds_g, lds_b, lds_h);
    }
}

// ---------------- final FC: out[32768,256] = y1[32768,512] @ fc_w[256,512]^T + b ----------
__global__ __launch_bounds__(256)
void fc_kernel(const u16* __restrict__ y1, const u16* __restrict__ fcw,
               const float* __restrict__ fcb, float* __restrict__ out)
{
    const int tid  = threadIdx.x;
    const int lane = tid & 63;
    const int wgid = blockIdx.x * 4 + (tid >> 6);  // 0..1023 waves
    const int nq   = wgid & 3;                     // 64-col block
    const int mt0  = wgid >> 2;                    // 0..255

    for (int j = 0; j < 8; ++j) {
        int mt = mt0 + j * 256;                    // M-tile 0..2047
        f32x4 acc[4] = {{0,0,0,0},{0,0,0,0},{0,0,0,0},{0,0,0,0}};
        const u16* arow = y1 + ((size_t)mt * 16 + (lane & 15)) * HID + (lane >> 4) * 8;
        #pragma unroll
        for (int ks = 0; ks < 16; ++ks) {
            short8 a = *reinterpret_cast<const short8*>(arow + ks * 32);
            #pragma unroll
            for (int nt = 0; nt < 4; ++nt) {
                const u16* brow = fcw + ((size_t)(nq * 64 + nt * 16 + (lane & 15))) * HID
                                      + ks * 32 + (lane >> 4) * 8;
                short8 b = *reinterpret_cast<const short8*>(brow);
                acc[nt] = __builtin_amdgcn_mfma_f32_16x16x32_bf16(a, b, acc[nt], 0, 0, 0);
            }
        }
        #pragma unroll
        for (int nt = 0; nt < 4; ++nt) {
            int col = nq * 64 + nt * 16 + (lane & 15);
            float bb = fcb[col];
            #pragma unroll
            for (int jj = 0; jj < 4; ++jj) {
                int row = mt * 16 + (lane >> 4) * 4 + jj;
                out[(size_t)row * OUTF + col] = acc[nt][jj] + bb;
            }
        }
    }
}

extern "C" void kernel_launch(void* const* d_in, const int* in_sizes, int n_in,
                              void* d_out, int out_size, void* d_ws, size_t ws_size,
                              hipStream_t stream)
{
    const float* x    = (const float*)d_in[0];
    const float* wih0 = (const float*)d_in[1];
    const float* whh0 = (const float*)d_in[2];
    const float* b0   = (const float*)d_in[3];
    const float* wih1 = (const float*)d_in[4];
    const float* whh1 = (const float*)d_in[5];
    const float* b1   = (const float*)d_in[6];
    const float* fcw  = (const float*)d_in[7];
    const float* fcb  = (const float*)d_in[8];
    float* out = (float*)d_out;

    const size_t flag_bytes = 512;   // flags0 line + flags1 line + pad

    char* ws = (char*)d_ws;
    size_t off = 0;
    unsigned* ctr = (unsigned*)ws;                    off += flag_bytes;
    u16* x_bf    = (u16*)(ws + off);                  off += (size_t)T_SEQ * BATCH * IN0 * 2;
    u16* wih0_bf = (u16*)(ws + off);                  off += (size_t)G4 * IN0 * 2;
    u16* whh0_bf = (u16*)(ws + off);                  off += (size_t)G4 * HID * 2;
    u16* wih1_bf = (u16*)(ws + off);                  off += (size_t)G4 * HID * 2;
    u16* whh1_bf = (u16*)(ws + off);                  off += (size_t)G4 * HID * 2;
    u16* fcw_bf  = (u16*)(ws + off);                  off += (size_t)OUTF * HID * 2;
    u16* y0      = (u16*)(ws + off);                  off += (size_t)T_SEQ * BATCH * HID * 2;
    u16* y1      = (u16*)(ws + off);                  off += (size_t)T_SEQ * BATCH * HID * 2;

    hipMemsetAsync(ctr, 0, flag_bytes, stream);

    auto conv = [&](const float* in, u16* o, int n) {
        int n4 = n / 4;
        cvt_f32_bf16<<<(n4 + 255) / 256, 256, 0, stream>>>(in, o, n4);
    };
    conv(x,    x_bf,    T_SEQ * BATCH * IN0);
    conv(wih0, wih0_bf, G4 * IN0);
    conv(whh0, whh0_bf, G4 * HID);
    conv(wih1, wih1_bf, G4 * HID);
    conv(whh1, whh1_bf, G4 * HID);
    conv(fcw,  fcw_bf,  OUTF * HID);

    float* outFC = out;
    float* hN = out + (size_t)T_SEQ * BATCH * OUTF;     // [2,B,H]
    float* cN = hN + 2 * BATCH * HID;                   // [2,B,H]

    lstm_fused<<<2 * NWG_L, NTHR, 0, stream>>>(x_bf, wih0_bf, whh0_bf, b0,
                                               wih1_bf, whh1_bf, b1,
                                               y0, y1, hN, cN, ctr);
    fc_kernel<<<256, 256, 0, stream>>>(y1, fcw_bf, fcb, outFC);
}

// Round 8
// 3838.437 us; speedup vs baseline: 1.3668x; 1.3668x over previous
//
#include <hip/hip_runtime.h>
#include <hip/hip_bf16.h>

#define T_SEQ 512
#define BATCH 64
#define IN0   128
#define HID   512
#define OUTF  256
#define G4    (4*HID)     // 2048 gate rows
#define NWG_L 64          // workgroups per layer (each owns 8 hidden units)
#define FSTR  32          // u32s between flags -> one 128B line per producer

typedef __attribute__((ext_vector_type(8))) short short8;   // 8 bf16 (MFMA A/B frag)
typedef __attribute__((ext_vector_type(4))) float f32x4;    // MFMA C/D frag
typedef unsigned short u16;

__device__ __forceinline__ float sigmoidf_(float x) { return 1.f / (1.f + __expf(-x)); }
__device__ __forceinline__ float tanhf_(float x)    { return 1.f - 2.f / (1.f + __expf(2.f * x)); }

__device__ __forceinline__ u16 f2bf(float f) {
    union { float f; unsigned u; } a; a.f = f;
    unsigned u = a.u;
    return (u16)((u + 0x7fffu + ((u >> 16) & 1u)) >> 16);   // RNE
}

// Poll: lane l watches flags[l*FSTR] (one 128B line per producer). Relaxed
// agent loads; rare acquire as progress safety net.
__device__ __forceinline__ void wave_poll_ge(const unsigned* flags, int lane, unsigned tgt) {
    unsigned it = 0;
    for (;;) {
        unsigned v = __hip_atomic_load(flags + (size_t)lane * FSTR,
                                       __ATOMIC_RELAXED, __HIP_MEMORY_SCOPE_AGENT);
        if (__all((int)(v >= tgt))) return;
        __builtin_amdgcn_s_sleep(1);
        if ((++it & 2047u) == 0u)
            (void)__hip_atomic_load(flags, __ATOMIC_ACQUIRE, __HIP_MEMORY_SCOPE_AGENT);
    }
}

// Intra-WG relay: waves spin on an LDS counter written by the polling wave.
__device__ __forceinline__ void lds_spin_ge(unsigned* p, unsigned tgt) {
    while (__hip_atomic_load(p, __ATOMIC_RELAXED, __HIP_MEMORY_SCOPE_WORKGROUP) < tgt)
        __builtin_amdgcn_s_sleep(1);
}

// 4x4 in-register transpose over (gate = lane bits[3:2]) x (vector elem = row).
// After: v = {i,f,g,o} gates for row j* = (lane>>2)&3, unit-offset du = lane&3.
__device__ __forceinline__ void gate_transpose(f32x4& v, int lane) {
    float t0 = __shfl_xor(v[0], 8), t1 = __shfl_xor(v[1], 8);
    float t2 = __shfl_xor(v[2], 8), t3 = __shfl_xor(v[3], 8);
    bool hi = (lane & 8) != 0;
    float y0 = hi ? t2 : v[0];
    float y1 = hi ? t3 : v[1];
    float y2 = hi ? v[2] : t0;
    float y3 = hi ? v[3] : t1;
    float u0 = __shfl_xor(y0, 4), u1 = __shfl_xor(y1, 4);
    float u2 = __shfl_xor(y2, 4), u3 = __shfl_xor(y3, 4);
    bool lo = (lane & 4) != 0;
    v[0] = lo ? u1 : y0;
    v[1] = lo ? y1 : u0;
    v[2] = lo ? u3 : y2;
    v[3] = lo ? y3 : u2;
}

// ---------------- f32 -> bf16 conversion ----------------
__global__ void cvt_f32_bf16(const float* __restrict__ in, u16* __restrict__ out, int n4) {
    int i = blockIdx.x * blockDim.x + threadIdx.x;
    if (i < n4) {
        float4 v = reinterpret_cast<const float4*>(in)[i];
        ushort4 o;
        o.x = f2bf(v.x); o.y = f2bf(v.y); o.z = f2bf(v.z); o.w = f2bf(v.w);
        reinterpret_cast<ushort4*>(out)[i] = o;
    }
}

// ---------------- fused pipelined 2-layer LSTM ----------------
// WG g in [0,64): layer 0, owns hidden units [8g, 8g+8) -> 32 gate rows as 2
// MFMA col-tiles. WG 64+g: layer 1, same ownership.
// Per step: poller waves relay global flags into LDS; all waves proceed
// independently (no barriers in the loop). Cell update fully in registers via
// gate_transpose; each wave publishes its own 16 rows; last wave to ack its
// stores raises the WG flag (LDS fetch_add election).
template<int LAYER>
__device__ __forceinline__ void run_layer(
    const u16* __restrict__ asrc,   // L0: x_bf [T,B,128]; L1: y0 [T,B,512]
    const u16* __restrict__ wih, const u16* __restrict__ whh,
    const float* __restrict__ bias,
    u16* __restrict__ ybuf,         // own-layer h/y storage [T,B,512]
    float* __restrict__ hNout, float* __restrict__ cNout,
    unsigned* flags_own, unsigned* flags_dep, int g,
    u16 (*lds_w)[32][512],
    unsigned* s_ready_own, unsigned* s_ready_dep, unsigned* s_done)
{
    constexpr int KIN = (LAYER == 0) ? IN0 : HID;
    constexpr int KS1 = KIN / 32;        // input-part K slices
    constexpr int KS  = KS1 + 16;        // + recurrent K slices

    const int tid  = threadIdx.x;
    const int lane = tid & 63;
    const int w    = tid >> 6;           // wave id -> batch rows 16w..16w+15
    const int ubase = 8 * g;

    // ---- pack weights into LDS in MFMA B-frag order (2 col-tiles) ----
    for (int idx = tid; idx < 2 * KS * 64; idx += 256) {
        int nt  = (idx >= KS * 64) ? 1 : 0;
        int rem = idx - nt * KS * 64;
        int ks = rem >> 6, s = rem & 63, q = s & 15, kq = s >> 4;
        int r = (q >> 2) * HID + ubase + 4 * nt + (q & 3);   // global gate row
        const u16* src = (ks < KS1)
            ? wih + (size_t)r * KIN + (size_t)ks * 32 + kq * 8
            : whh + (size_t)r * HID + (size_t)(ks - KS1) * 32 + kq * 8;
        *reinterpret_cast<uint4*>(&lds_w[nt][ks][s * 8]) =
            *reinterpret_cast<const uint4*>(src);
    }
    if (tid == 0) { *s_ready_own = 0; *s_ready_dep = 0; *s_done = 0; }
    __syncthreads();

    // per-lane geometry
    const int arow = 16 * w + (lane & 15);   // MFMA A row (batch)
    const int koff = (lane >> 4) * 8;
    const int du   = lane & 3;               // unit offset within tile
    const int myrow = 16 * w + 4 * (lane >> 4) + ((lane >> 2) & 3);  // cell row
    const int u0 = ubase + du, u1 = ubase + 4 + du;
    const float bi0 = bias[0*HID + u0], bf0 = bias[1*HID + u0],
                bg0 = bias[2*HID + u0], bo0 = bias[3*HID + u0];
    const float bi1 = bias[0*HID + u1], bf1 = bias[1*HID + u1],
                bg1 = bias[2*HID + u1], bo1 = bias[3*HID + u1];

    float c0 = 0.f, c1 = 0.f;

    for (int t = 0; t < T_SEQ; ++t) {
        f32x4 ac0[4] = {{0,0,0,0},{0,0,0,0},{0,0,0,0},{0,0,0,0}};
        f32x4 ac1[4] = {{0,0,0,0},{0,0,0,0},{0,0,0,0},{0,0,0,0}};

        // ---- pollers relay global flags into LDS ----
        if (w == 0 && t > 0) {
            wave_poll_ge(flags_own, lane, (unsigned)t);
            __hip_atomic_store(s_ready_own, (unsigned)t,
                               __ATOMIC_RELAXED, __HIP_MEMORY_SCOPE_WORKGROUP);
        }
        if (LAYER == 1 && w == 1) {
            wave_poll_ge(flags_dep, lane, (unsigned)(t + 1));
            __hip_atomic_store(s_ready_dep, (unsigned)(t + 1),
                               __ATOMIC_RELAXED, __HIP_MEMORY_SCOPE_WORKGROUP);
        }

        // ---- input GEMM ----
        if (LAYER == 0) {
            const u16* ap = asrc + ((size_t)t * BATCH + arow) * KIN + koff;
            short8 a[KS1];
            #pragma unroll
            for (int j = 0; j < KS1; ++j)
                a[j] = *reinterpret_cast<const short8*>(ap + j * 32);
            #pragma unroll
            for (int j = 0; j < KS1; ++j) {
                ac0[j & 3] = __builtin_amdgcn_mfma_f32_16x16x32_bf16(
                    a[j], *reinterpret_cast<const short8*>(&lds_w[0][j][lane * 8]), ac0[j & 3], 0, 0, 0);
                ac1[j & 3] = __builtin_amdgcn_mfma_f32_16x16x32_bf16(
                    a[j], *reinterpret_cast<const short8*>(&lds_w[1][j][lane * 8]), ac1[j & 3], 0, 0, 0);
            }
        } else {
            lds_spin_ge(s_ready_dep, (unsigned)(t + 1));     // y0[t] ready
            const u16* ap = asrc + ((size_t)t * BATCH + arow) * HID + koff;
            short8 a[16];
            #pragma unroll
            for (int j = 0; j < 16; ++j)
                a[j] = *reinterpret_cast<const short8*>(ap + j * 32);
            #pragma unroll
            for (int j = 0; j < 16; ++j) {
                ac0[j & 3] = __builtin_amdgcn_mfma_f32_16x16x32_bf16(
                    a[j], *reinterpret_cast<const short8*>(&lds_w[0][j][lane * 8]), ac0[j & 3], 0, 0, 0);
                ac1[j & 3] = __builtin_amdgcn_mfma_f32_16x16x32_bf16(
                    a[j], *reinterpret_cast<const short8*>(&lds_w[1][j][lane * 8]), ac1[j & 3], 0, 0, 0);
            }
        }

        // ---- recurrent GEMM (h[t-1]) ----
        if (t > 0) {
            lds_spin_ge(s_ready_own, (unsigned)t);
            const u16* hp = ybuf + ((size_t)(t - 1) * BATCH + arow) * HID + koff;
            short8 a[16];
            #pragma unroll
            for (int j = 0; j < 16; ++j)
                a[j] = *reinterpret_cast<const short8*>(hp + j * 32);
            #pragma unroll
            for (int j = 0; j < 16; ++j) {
                ac0[j & 3] = __builtin_amdgcn_mfma_f32_16x16x32_bf16(
                    a[j], *reinterpret_cast<const short8*>(&lds_w[0][KS1 + j][lane * 8]), ac0[j & 3], 0, 0, 0);
                ac1[j & 3] = __builtin_amdgcn_mfma_f32_16x16x32_bf16(
                    a[j], *reinterpret_cast<const short8*>(&lds_w[1][KS1 + j][lane * 8]), ac1[j & 3], 0, 0, 0);
            }
        }

        f32x4 s0 = (ac0[0] + ac0[1]) + (ac0[2] + ac0[3]);
        f32x4 s1 = (ac1[0] + ac1[1]) + (ac1[2] + ac1[3]);

        // ---- in-register gate redistribution (no LDS, no barrier) ----
        gate_transpose(s0, lane);   // -> {i,f,g,o} for (myrow, unit u0)
        gate_transpose(s1, lane);   // -> {i,f,g,o} for (myrow, unit u1)

        // ---- cell update ----
        float gi0 = sigmoidf_(s0[0] + bi0);
        float gf0 = sigmoidf_(s0[1] + bf0);
        float gg0 = tanhf_(   s0[2] + bg0);
        float go0 = sigmoidf_(s0[3] + bo0);
        c0 = gf0 * c0 + gi0 * gg0;
        float h0v = go0 * tanhf_(c0);
        float gi1 = sigmoidf_(s1[0] + bi1);
        float gf1 = sigmoidf_(s1[1] + bf1);
        float gg1 = tanhf_(   s1[2] + bg1);
        float go1 = sigmoidf_(s1[3] + bo1);
        c1 = gf1 * c1 + gi1 * gg1;
        float h1v = go1 * tanhf_(c1);

        // ---- per-wave publish: pair lanes (du, du^1) into u32 words ----
        float p0 = __shfl_xor(h0v, 1);
        float p1 = __shfl_xor(h1v, 1);
        if ((du & 1) == 0) {
            unsigned w0v = (unsigned)f2bf(h0v) | ((unsigned)f2bf(p0) << 16);
            unsigned w1v = (unsigned)f2bf(h1v) | ((unsigned)f2bf(p1) << 16);
            u16* rb = ybuf + ((size_t)t * BATCH + myrow) * HID;
            __hip_atomic_store(reinterpret_cast<unsigned*>(rb + u0), w0v,
                               __ATOMIC_RELAXED, __HIP_MEMORY_SCOPE_AGENT);
            __hip_atomic_store(reinterpret_cast<unsigned*>(rb + u1), w1v,
                               __ATOMIC_RELAXED, __HIP_MEMORY_SCOPE_AGENT);
        }
        if (t == T_SEQ - 1) {
            hNout[myrow * HID + u0] = h0v;
            hNout[myrow * HID + u1] = h1v;
            cNout[myrow * HID + u0] = c0;
            cNout[myrow * HID + u1] = c1;
        }

        // wave-level ack, then last-acker raises the WG flag
        asm volatile("s_waitcnt vmcnt(0)" ::: "memory");
        if (lane == 0) {
            unsigned old = __hip_atomic_fetch_add(s_done, 1u,
                               __ATOMIC_RELAXED, __HIP_MEMORY_SCOPE_WORKGROUP);
            if (old == (unsigned)(4 * t + 3))
                __hip_atomic_store(flags_own + (size_t)g * FSTR, (unsigned)(t + 1),
                                   __ATOMIC_RELAXED, __HIP_MEMORY_SCOPE_AGENT);
        }
    }
}

__global__ __launch_bounds__(256, 1)
void lstm_fused(const u16* __restrict__ x_bf,
                const u16* __restrict__ wih0, const u16* __restrict__ whh0, const float* __restrict__ b0,
                const u16* __restrict__ wih1, const u16* __restrict__ whh1, const float* __restrict__ b1,
                u16* __restrict__ y0, u16* __restrict__ y1,
                float* __restrict__ hN, float* __restrict__ cN,
                unsigned* __restrict__ ctr)
{
    __shared__ __align__(16) u16 lds_w[2][32][512];   // 64 KB (L0 uses KS=20 of 32)
    __shared__ unsigned s_ready_own, s_ready_dep, s_done;

    unsigned* flags0 = ctr;
    unsigned* flags1 = ctr + NWG_L * FSTR;

    const int wgid = blockIdx.x;
    if (wgid < NWG_L) {
        run_layer<0>(x_bf, wih0, whh0, b0, y0, hN, cN,
                     flags0, flags0, wgid, lds_w,
                     &s_ready_own, &s_ready_dep, &s_done);
    } else {
        run_layer<1>(y0, wih1, whh1, b1, y1, hN + BATCH * HID, cN + BATCH * HID,
                     flags1, flags0, wgid - NWG_L, lds_w,
                     &s_ready_own, &s_ready_dep, &s_done);
    }
}

// ---------------- final FC: out[32768,256] = y1[32768,512] @ fc_w[256,512]^T + b ----------
__global__ __launch_bounds__(256)
void fc_kernel(const u16* __restrict__ y1, const u16* __restrict__ fcw,
               const float* __restrict__ fcb, float* __restrict__ out)
{
    const int tid  = threadIdx.x;
    const int lane = tid & 63;
    const int wgid = blockIdx.x * 4 + (tid >> 6);  // 0..1023 waves
    const int nq   = wgid & 3;                     // 64-col block
    const int mt0  = wgid >> 2;                    // 0..255

    for (int j = 0; j < 8; ++j) {
        int mt = mt0 + j * 256;                    // M-tile 0..2047
        f32x4 acc[4] = {{0,0,0,0},{0,0,0,0},{0,0,0,0},{0,0,0,0}};
        const u16* arow = y1 + ((size_t)mt * 16 + (lane & 15)) * HID + (lane >> 4) * 8;
        #pragma unroll
        for (int ks = 0; ks < 16; ++ks) {
            short8 a = *reinterpret_cast<const short8*>(arow + ks * 32);
            #pragma unroll
            for (int nt = 0; nt < 4; ++nt) {
                const u16* brow = fcw + ((size_t)(nq * 64 + nt * 16 + (lane & 15))) * HID
                                      + ks * 32 + (lane >> 4) * 8;
                short8 b = *reinterpret_cast<const short8*>(brow);
                acc[nt] = __builtin_amdgcn_mfma_f32_16x16x32_bf16(a, b, acc[nt], 0, 0, 0);
            }
        }
        #pragma unroll
        for (int nt = 0; nt < 4; ++nt) {
            int col = nq * 64 + nt * 16 + (lane & 15);
            float bb = fcb[col];
            #pragma unroll
            for (int jj = 0; jj < 4; ++jj) {
                int row = mt * 16 + (lane >> 4) * 4 + jj;
                out[(size_t)row * OUTF + col] = acc[nt][jj] + bb;
            }
        }
    }
}

extern "C" void kernel_launch(void* const* d_in, const int* in_sizes, int n_in,
                              void* d_out, int out_size, void* d_ws, size_t ws_size,
                              hipStream_t stream)
{
    const float* x    = (const float*)d_in[0];
    const float* wih0 = (const float*)d_in[1];
    const float* whh0 = (const float*)d_in[2];
    const float* b0   = (const float*)d_in[3];
    const float* wih1 = (const float*)d_in[4];
    const float* whh1 = (const float*)d_in[5];
    const float* b1   = (const float*)d_in[6];
    const float* fcw  = (const float*)d_in[7];
    const float* fcb  = (const float*)d_in[8];
    float* out = (float*)d_out;

    const size_t flag_bytes = (size_t)2 * NWG_L * FSTR * 4;   // 16 KB

    char* ws = (char*)d_ws;
    size_t off = 0;
    unsigned* ctr = (unsigned*)ws;                    off += flag_bytes;
    u16* x_bf    = (u16*)(ws + off);                  off += (size_t)T_SEQ * BATCH * IN0 * 2;
    u16* wih0_bf = (u16*)(ws + off);                  off += (size_t)G4 * IN0 * 2;
    u16* whh0_bf = (u16*)(ws + off);                  off += (size_t)G4 * HID * 2;
    u16* wih1_bf = (u16*)(ws + off);                  off += (size_t)G4 * HID * 2;
    u16* whh1_bf = (u16*)(ws + off);                  off += (size_t)G4 * HID * 2;
    u16* fcw_bf  = (u16*)(ws + off);                  off += (size_t)OUTF * HID * 2;
    u16* y0      = (u16*)(ws + off);                  off += (size_t)T_SEQ * BATCH * HID * 2;
    u16* y1      = (u16*)(ws + off);                  off += (size_t)T_SEQ * BATCH * HID * 2;

    hipMemsetAsync(ctr, 0, flag_bytes, stream);

    auto conv = [&](const float* in, u16* o, int n) {
        int n4 = n / 4;
        cvt_f32_bf16<<<(n4 + 255) / 256, 256, 0, stream>>>(in, o, n4);
    };
    conv(x,    x_bf,    T_SEQ * BATCH * IN0);
    conv(wih0, wih0_bf, G4 * IN0);
    conv(whh0, whh0_bf, G4 * HID);
    conv(wih1, wih1_bf, G4 * HID);
    conv(whh1, whh1_bf, G4 * HID);
    conv(fcw,  fcw_bf,  OUTF * HID);

    float* outFC = out;
    float* hN = out + (size_t)T_SEQ * BATCH * OUTF;     // [2,B,H]
    float* cN = hN + 2 * BATCH * HID;                   // [2,B,H]

    lstm_fused<<<2 * NWG_L, 256, 0, stream>>>(x_bf, wih0_bf, whh0_bf, b0,
                                              wih1_bf, whh1_bf, b1,
                                              y0, y1, hN, cN, ctr);
    fc_kernel<<<256, 256, 0, stream>>>(y1, fcw_bf, fcb, outFC);
}